// Round 2
// baseline (1059.140 us; speedup 1.0000x reference)
//
#include <hip/hip_runtime.h>

#define BB 8
#define CC 256
#define TT 4
#define NNv 4096
#define HH 1024
#define LLv (TT*NNv)   // 16384

typedef short bf16x8 __attribute__((ext_vector_type(8)));
typedef float f32x4 __attribute__((ext_vector_type(4)));

static __device__ __forceinline__ float bfbits2f(unsigned short h) {
    return __uint_as_float(((unsigned int)h) << 16);
}
static __device__ __forceinline__ unsigned short f2bf(float f) {
    unsigned int u = __float_as_uint(f);
    return (unsigned short)((u + 0x7FFFu + ((u >> 16) & 1u)) >> 16);
}

// ---- split fp32 weights into bf16 parts; products with {0,1} spikes are exact ----
__global__ __launch_bounds__(256) void k_split3(const float* __restrict__ w,
    unsigned short* __restrict__ hi, unsigned short* __restrict__ mid,
    unsigned short* __restrict__ lo, int n)
{
    int i = blockIdx.x * 256 + threadIdx.x;
    if (i >= n) return;
    float x = w[i];
    unsigned short h = f2bf(x); float r  = __fsub_rn(x, bfbits2f(h));
    unsigned short m = f2bf(r); float r2 = __fsub_rn(r, bfbits2f(m));
    unsigned short l = f2bf(r2);
    hi[i] = h; mid[i] = m; lo[i] = l;
}

__global__ __launch_bounds__(256) void k_split2(const float* __restrict__ w,
    unsigned short* __restrict__ hi, unsigned short* __restrict__ lo, int n)
{
    int i = blockIdx.x * 256 + threadIdx.x;
    if (i >= n) return;
    float x = w[i];
    unsigned short h = f2bf(x); float r = __fsub_rn(x, bfbits2f(h));
    unsigned short l = f2bf(r);
    hi[i] = h; lo[i] = l;
}

// ---------------- bn2 + LIF over T (fp32, mirrors ref op order), spikes as u8 ----------------
__global__ __launch_bounds__(256) void k_bn2_lif(
    const float* __restrict__ x,
    const float* __restrict__ g, const float* __restrict__ be,
    const float* __restrict__ mu, const float* __restrict__ va,
    unsigned char* __restrict__ s1)
{
    int tid = blockIdx.x * 256 + threadIdx.x;   // B*C*N/8 threads
    int bc = tid >> 9;
    int n8 = (tid & 511) << 3;
    int c = bc & (CC - 1);
    float rsq = __fdiv_rn(1.0f, __fsqrt_rn(__fadd_rn(va[c], 1e-5f)));
    float inv = __fmul_rn(g[c], rsq);
    float add = __fsub_rn(be[c], __fmul_rn(mu[c], inv));
    size_t base = (size_t)bc * LLv + n8;
    float v[8];
    #pragma unroll
    for (int i = 0; i < 8; i++) v[i] = 0.0f;
    #pragma unroll
    for (int t = 0; t < TT; t++) {
        float4 p0 = *(const float4*)(x + base + t * NNv);
        float4 p1 = *(const float4*)(x + base + t * NNv + 4);
        float xp[8] = {p0.x, p0.y, p0.z, p0.w, p1.x, p1.y, p1.z, p1.w};
        unsigned long long ob = 0ull;
        #pragma unroll
        for (int i = 0; i < 8; i++) {
            float y = __fadd_rn(__fmul_rn(xp[i], inv), add);
            float vv = __fadd_rn(v[i], __fdiv_rn(__fsub_rn(y, v[i]), 1.5f));
            bool sp = vv >= 1.0f;
            v[i] = sp ? 0.0f : vv;
            if (sp) ob |= (1ull << (8 * i));
        }
        *(unsigned long long*)(s1 + base + t * NNv) = ob;
    }
}

// ------- GEMM1 (fc1) 3-split bf16 MFMA + bias + bn1 + LIF scan, spikes u8 -------
__global__ __launch_bounds__(256) void k_gemm1_lif(
    const unsigned short* __restrict__ w1h, const unsigned short* __restrict__ w1m,
    const unsigned short* __restrict__ w1l,
    const float* __restrict__ b1,
    const float* __restrict__ g1, const float* __restrict__ be1,
    const float* __restrict__ mu1, const float* __restrict__ va1,
    const unsigned char* __restrict__ s1, unsigned char* __restrict__ s2)
{
    __shared__ unsigned short Ws[3][64][72];   // [split][h][k-chunk64]
    __shared__ unsigned short Ss[64][72];      // [n][k-chunk64]
    const int tx = threadIdx.x;
    const int n0 = blockIdx.x * 64;
    const int h0 = blockIdx.y * 64;
    const int b  = blockIdx.z;
    const int lane = tx & 63, w = tx >> 6;
    const int q = lane >> 4, ln = lane & 15;
    const int wh = (w & 1) * 32, wn = (w >> 1) * 32;

    f32x4 acc[TT][2][2];
    #pragma unroll
    for (int t = 0; t < TT; t++)
    #pragma unroll
    for (int mi = 0; mi < 2; mi++)
    #pragma unroll
    for (int ni = 0; ni < 2; ni++)
        acc[t][mi][ni] = (f32x4){0.f, 0.f, 0.f, 0.f};

    for (int ko = 0; ko < CC; ko += 64) {
        __syncthreads();
        // stage 3 weight splits [64][64]
        #pragma unroll
        for (int i = 0; i < 6; i++) {
            const unsigned short* wp = (i < 2) ? w1h : (i < 4) ? w1m : w1l;
            int rem = (i & 1) * 256 + tx;
            int hh = rem >> 3, cb = rem & 7;
            *(uint4*)&Ws[i >> 1][hh][cb * 8] =
                *(const uint4*)(wp + (size_t)(h0 + hh) * CC + ko + cb * 8);
        }
        for (int t = 0; t < TT; t++) {
            __syncthreads();   // protect previous Ss readers (and Ws at t=0)
            #pragma unroll
            for (int i = 0; i < 2; i++) {
                int task = i * 256 + tx;
                int nb = task & 7, cc2 = task >> 3;   // cc2: 0..63
                unsigned long long d = *(const unsigned long long*)(
                    s1 + ((size_t)b * CC + ko + cc2) * LLv + t * NNv + n0 + nb * 8);
                #pragma unroll
                for (int j = 0; j < 8; j++)
                    Ss[nb * 8 + j][cc2] = ((d >> (8 * j)) & 0xFFull) ? 0x3F80 : 0;
            }
            __syncthreads();
            #pragma unroll
            for (int kb = 0; kb < 2; kb++) {
                bf16x8 bfr[2];
                bfr[0] = *(const bf16x8*)&Ss[wn + ln][kb * 32 + q * 8];
                bfr[1] = *(const bf16x8*)&Ss[wn + 16 + ln][kb * 32 + q * 8];
                #pragma unroll
                for (int s = 0; s < 3; s++) {
                    bf16x8 a0 = *(const bf16x8*)&Ws[s][wh + ln][kb * 32 + q * 8];
                    bf16x8 a1 = *(const bf16x8*)&Ws[s][wh + 16 + ln][kb * 32 + q * 8];
                    acc[t][0][0] = __builtin_amdgcn_mfma_f32_16x16x32_bf16(a0, bfr[0], acc[t][0][0], 0, 0, 0);
                    acc[t][0][1] = __builtin_amdgcn_mfma_f32_16x16x32_bf16(a0, bfr[1], acc[t][0][1], 0, 0, 0);
                    acc[t][1][0] = __builtin_amdgcn_mfma_f32_16x16x32_bf16(a1, bfr[0], acc[t][1][0], 0, 0, 0);
                    acc[t][1][1] = __builtin_amdgcn_mfma_f32_16x16x32_bf16(a1, bfr[1], acc[t][1][1], 0, 0, 0);
                }
            }
        }
    }

    // epilogue: bias + bn1 + LIF scan over t (fp32, ref op order)
    #pragma unroll
    for (int mi = 0; mi < 2; mi++)
    #pragma unroll
    for (int r = 0; r < 4; r++) {
        int h = h0 + wh + mi * 16 + q * 4 + r;
        float rsq = __fdiv_rn(1.0f, __fsqrt_rn(__fadd_rn(va1[h], 1e-5f)));
        float inv = __fmul_rn(g1[h], rsq);
        float add = __fsub_rn(be1[h], __fmul_rn(mu1[h], inv));
        float bias = b1[h];
        #pragma unroll
        for (int ni = 0; ni < 2; ni++) {
            int l0 = n0 + wn + ni * 16 + ln;
            float v = 0.0f;
            #pragma unroll
            for (int t = 0; t < TT; t++) {
                float h1 = __fadd_rn(acc[t][mi][ni][r], bias);
                float y  = __fadd_rn(__fmul_rn(h1, inv), add);
                float vv = __fadd_rn(v, __fdiv_rn(__fsub_rn(y, v), 1.5f));
                bool sp = vv >= 1.0f;
                v = sp ? 0.0f : vv;
                s2[((size_t)b * HH + h) * LLv + t * NNv + l0] = sp ? 1 : 0;
            }
        }
    }
}

// ------------- GEMM2 (fc2) 2-split bf16 MFMA + bias, fp32 output -------------
__global__ __launch_bounds__(256) void k_gemm2(
    const unsigned short* __restrict__ w2h, const unsigned short* __restrict__ w2l,
    const float* __restrict__ b2c,
    const unsigned char* __restrict__ s2, float* __restrict__ outp)
{
    __shared__ unsigned short Ws[2][64][136];  // [split][c][k-chunk128]
    __shared__ unsigned short Ss[64][136];     // [l][k-chunk128]
    const int tx = threadIdx.x;
    const int l0 = blockIdx.x * 64;
    const int c0 = blockIdx.y * 64;
    const int b  = blockIdx.z;
    const int lane = tx & 63, w = tx >> 6;
    const int q = lane >> 4, ln = lane & 15;
    const int wh = (w & 1) * 32, wn = (w >> 1) * 32;

    f32x4 acc[2][2];
    #pragma unroll
    for (int mi = 0; mi < 2; mi++)
    #pragma unroll
    for (int ni = 0; ni < 2; ni++)
        acc[mi][ni] = (f32x4){0.f, 0.f, 0.f, 0.f};

    for (int ko = 0; ko < HH; ko += 128) {
        __syncthreads();
        #pragma unroll
        for (int i = 0; i < 8; i++) {
            const unsigned short* wp = (i < 4) ? w2h : w2l;
            int rem = (i & 3) * 256 + tx;
            int hh = rem >> 4, cb = rem & 15;
            *(uint4*)&Ws[i >> 2][hh][cb * 8] =
                *(const uint4*)(wp + (size_t)(c0 + hh) * HH + ko + cb * 8);
        }
        #pragma unroll
        for (int i = 0; i < 4; i++) {
            int task = i * 256 + tx;
            int nb = task & 7, hh = task >> 3;   // hh: 0..127
            unsigned long long d = *(const unsigned long long*)(
                s2 + ((size_t)b * HH + ko + hh) * LLv + l0 + nb * 8);
            #pragma unroll
            for (int j = 0; j < 8; j++)
                Ss[nb * 8 + j][hh] = ((d >> (8 * j)) & 0xFFull) ? 0x3F80 : 0;
        }
        __syncthreads();
        #pragma unroll
        for (int kb = 0; kb < 4; kb++) {
            bf16x8 bfr[2];
            bfr[0] = *(const bf16x8*)&Ss[wn + ln][kb * 32 + q * 8];
            bfr[1] = *(const bf16x8*)&Ss[wn + 16 + ln][kb * 32 + q * 8];
            #pragma unroll
            for (int s = 0; s < 2; s++) {
                bf16x8 a0 = *(const bf16x8*)&Ws[s][wh + ln][kb * 32 + q * 8];
                bf16x8 a1 = *(const bf16x8*)&Ws[s][wh + 16 + ln][kb * 32 + q * 8];
                acc[0][0] = __builtin_amdgcn_mfma_f32_16x16x32_bf16(a0, bfr[0], acc[0][0], 0, 0, 0);
                acc[0][1] = __builtin_amdgcn_mfma_f32_16x16x32_bf16(a0, bfr[1], acc[0][1], 0, 0, 0);
                acc[1][0] = __builtin_amdgcn_mfma_f32_16x16x32_bf16(a1, bfr[0], acc[1][0], 0, 0, 0);
                acc[1][1] = __builtin_amdgcn_mfma_f32_16x16x32_bf16(a1, bfr[1], acc[1][1], 0, 0, 0);
            }
        }
    }
    #pragma unroll
    for (int mi = 0; mi < 2; mi++)
    #pragma unroll
    for (int r = 0; r < 4; r++) {
        int c = c0 + wh + mi * 16 + q * 4 + r;
        float bias = b2c[c];
        #pragma unroll
        for (int ni = 0; ni < 2; ni++) {
            float o = __fadd_rn(acc[mi][ni][r], bias);
            outp[((size_t)b * CC + c) * LLv + l0 + wn + ni * 16 + ln] = o;
        }
    }
}

extern "C" void kernel_launch(void* const* d_in, const int* in_sizes, int n_in,
                              void* d_out, int out_size, void* d_ws, size_t ws_size,
                              hipStream_t stream) {
    const float* x    = (const float*)d_in[0];
    const float* fc1w = (const float*)d_in[1];
    const float* fc1b = (const float*)d_in[2];
    const float* fc2w = (const float*)d_in[3];
    const float* fc2b = (const float*)d_in[4];
    const float* g1   = (const float*)d_in[5];
    const float* be1  = (const float*)d_in[6];
    const float* mu1  = (const float*)d_in[7];
    const float* va1  = (const float*)d_in[8];
    const float* g2   = (const float*)d_in[9];
    const float* be2  = (const float*)d_in[10];
    const float* mu2  = (const float*)d_in[11];
    const float* va2  = (const float*)d_in[12];

    const size_t WN = (size_t)HH * CC;              // 262144 weights each
    unsigned short* w1h = (unsigned short*)d_ws;
    unsigned short* w1m = w1h + WN;
    unsigned short* w1l = w1m + WN;
    unsigned short* w2h = w1l + WN;
    unsigned short* w2l = w2h + WN;
    unsigned char*  s1  = (unsigned char*)(w2l + WN);          // 33.5 MB
    unsigned char*  s2  = s1 + (size_t)BB * CC * LLv;          // 134 MB
    float* outp = (float*)d_out;

    hipLaunchKernelGGL(k_split3, dim3(WN / 256), dim3(256), 0, stream, fc1w, w1h, w1m, w1l, (int)WN);
    hipLaunchKernelGGL(k_split2, dim3(WN / 256), dim3(256), 0, stream, fc2w, w2h, w2l, (int)WN);
    hipLaunchKernelGGL(k_bn2_lif, dim3((BB * CC * NNv / 8) / 256), dim3(256), 0, stream,
                       x, g2, be2, mu2, va2, s1);
    hipLaunchKernelGGL(k_gemm1_lif, dim3(NNv / 64, HH / 64, BB), dim3(256), 0, stream,
                       w1h, w1m, w1l, fc1b, g1, be1, mu1, va1, s1, s2);
    hipLaunchKernelGGL(k_gemm2, dim3(LLv / 64, CC / 64, BB), dim3(256), 0, stream,
                       w2h, w2l, fc2b, s2, outp);
}

// Round 3
// 709.545 us; speedup vs baseline: 1.4927x; 1.4927x over previous
//
#include <hip/hip_runtime.h>

#define BB 8
#define CC 256
#define TT 4
#define NNv 4096
#define HH 1024
#define LLv (TT*NNv)   // 16384

typedef short bf16x8 __attribute__((ext_vector_type(8)));
typedef float f32x4 __attribute__((ext_vector_type(4)));

static __device__ __forceinline__ float bfbits2f(unsigned short h) {
    return __uint_as_float(((unsigned int)h) << 16);
}
static __device__ __forceinline__ unsigned short f2bf(float f) {
    unsigned int u = __float_as_uint(f);
    return (unsigned short)((u + 0x7FFFu + ((u >> 16) & 1u)) >> 16);
}

// ---- split fp32 weights into bf16 parts; products with {0,1} spikes are exact ----
// k-index low 3 bits permuted: original j -> position (j>>1) + ((j&1)<<2), matching
// the {0,2,4,6,1,3,5,7} emission order of the spike byte->bf16 mul trick.
__global__ __launch_bounds__(256) void k_split3(const float* __restrict__ w,
    unsigned short* __restrict__ hi, unsigned short* __restrict__ mid,
    unsigned short* __restrict__ lo, int n)
{
    int i = blockIdx.x * 256 + threadIdx.x;
    if (i >= n) return;
    float x = w[i];
    int j = i & 7;
    int ip = (i & ~7) | ((j >> 1) + ((j & 1) << 2));
    unsigned short h = f2bf(x); float r  = __fsub_rn(x, bfbits2f(h));
    unsigned short m = f2bf(r); float r2 = __fsub_rn(r, bfbits2f(m));
    unsigned short l = f2bf(r2);
    hi[ip] = h; mid[ip] = m; lo[ip] = l;
}

__global__ __launch_bounds__(256) void k_split2(const float* __restrict__ w,
    unsigned short* __restrict__ hi, unsigned short* __restrict__ lo, int n)
{
    int i = blockIdx.x * 256 + threadIdx.x;
    if (i >= n) return;
    float x = w[i];
    int j = i & 7;
    int ip = (i & ~7) | ((j >> 1) + ((j & 1) << 2));
    unsigned short h = f2bf(x); float r = __fsub_rn(x, bfbits2f(h));
    unsigned short l = f2bf(r);
    hi[ip] = h; lo[ip] = l;
}

// ---------------- bn2 + LIF over T (fp32, mirrors ref op order), spikes as u8 ----------------
__global__ __launch_bounds__(256) void k_bn2_lif(
    const float* __restrict__ x,
    const float* __restrict__ g, const float* __restrict__ be,
    const float* __restrict__ mu, const float* __restrict__ va,
    unsigned char* __restrict__ s1)
{
    int tid = blockIdx.x * 256 + threadIdx.x;   // B*C*N/8 threads
    int bc = tid >> 9;
    int n8 = (tid & 511) << 3;
    int c = bc & (CC - 1);
    float rsq = __fdiv_rn(1.0f, __fsqrt_rn(__fadd_rn(va[c], 1e-5f)));
    float inv = __fmul_rn(g[c], rsq);
    float add = __fsub_rn(be[c], __fmul_rn(mu[c], inv));
    size_t base = (size_t)bc * LLv + n8;
    float v[8];
    #pragma unroll
    for (int i = 0; i < 8; i++) v[i] = 0.0f;
    #pragma unroll
    for (int t = 0; t < TT; t++) {
        float4 p0 = *(const float4*)(x + base + t * NNv);
        float4 p1 = *(const float4*)(x + base + t * NNv + 4);
        float xp[8] = {p0.x, p0.y, p0.z, p0.w, p1.x, p1.y, p1.z, p1.w};
        unsigned long long ob = 0ull;
        #pragma unroll
        for (int i = 0; i < 8; i++) {
            float y = __fadd_rn(__fmul_rn(xp[i], inv), add);
            float vv = __fadd_rn(v[i], __fdiv_rn(__fsub_rn(y, v[i]), 1.5f));
            bool sp = vv >= 1.0f;
            v[i] = sp ? 0.0f : vv;
            if (sp) ob |= (1ull << (8 * i));
        }
        *(unsigned long long*)(s1 + base + t * NNv) = ob;
    }
}

// -------- transpose s1[b][c][t][n] -> s1T[b][t][n][c] (64x64 byte tiles) --------
__global__ __launch_bounds__(256) void k_transpose(
    const unsigned char* __restrict__ s1, unsigned char* __restrict__ s1T)
{
    __shared__ unsigned char tile[64][80];   // stride 80: 16B-aligned rows
    int tx = threadIdx.x;
    int n0 = blockIdx.x * 64;
    int c0 = blockIdx.y * 64;
    int bt = blockIdx.z;          // b*4 + t
    int b = bt >> 2, t = bt & 3;
    int cr = tx >> 2, cc = tx & 3;
    *(uint4*)&tile[cr][cc * 16] = *(const uint4*)(
        s1 + ((size_t)(b * CC + c0 + cr) * TT + t) * NNv + n0 + cc * 16);
    __syncthreads();
    int nr = tx >> 2, cg = tx & 3;
    unsigned char outv[16];
    #pragma unroll
    for (int j = 0; j < 16; j++) outv[j] = tile[cg * 16 + j][nr];
    *(uint4*)(s1T + ((size_t)bt * NNv + n0 + nr) * CC + c0 + cg * 16) = *(uint4*)outv;
}

// byte->bf16 {0,1} expansion: emits k-order {0,2,4,6,1,3,5,7} (weights pre-permuted)
static __device__ __forceinline__ uint4 spikes8_to_bf16(unsigned long long d) {
    unsigned int lo = (unsigned int)d, hi = (unsigned int)(d >> 32);
    uint4 o;
    o.x = (lo & 0x10001u) * 0x3F80u;
    o.y = (hi & 0x10001u) * 0x3F80u;
    o.z = ((lo >> 8) & 0x10001u) * 0x3F80u;
    o.w = ((hi >> 8) & 0x10001u) * 0x3F80u;
    return o;
}

// ------- GEMM1 (fc1) 3-split bf16 MFMA + bias + bn1 + LIF scan, spikes -> s2T[b][l][h] -------
__global__ __launch_bounds__(256) void k_gemm1_lif(
    const unsigned short* __restrict__ w1h, const unsigned short* __restrict__ w1m,
    const unsigned short* __restrict__ w1l,
    const float* __restrict__ b1,
    const float* __restrict__ g1, const float* __restrict__ be1,
    const float* __restrict__ mu1, const float* __restrict__ va1,
    const unsigned char* __restrict__ s1T, unsigned char* __restrict__ s2T)
{
    __shared__ unsigned short Ws[3][64][72];
    __shared__ unsigned short Ss[64][72];
    const int tx = threadIdx.x;
    const int n0 = blockIdx.x * 64;
    const int h0 = blockIdx.y * 64;
    const int b  = blockIdx.z;
    const int lane = tx & 63, w = tx >> 6;
    const int q = lane >> 4, ln = lane & 15;
    const int wh = (w & 1) * 32, wn = (w >> 1) * 32;

    f32x4 acc[TT][2][2];
    #pragma unroll
    for (int t = 0; t < TT; t++)
    #pragma unroll
    for (int mi = 0; mi < 2; mi++)
    #pragma unroll
    for (int ni = 0; ni < 2; ni++)
        acc[t][mi][ni] = (f32x4){0.f, 0.f, 0.f, 0.f};

    for (int ko = 0; ko < CC; ko += 64) {
        __syncthreads();
        #pragma unroll
        for (int i = 0; i < 6; i++) {
            const unsigned short* wp = (i < 2) ? w1h : (i < 4) ? w1m : w1l;
            int rem = (i & 1) * 256 + tx;
            int hh = rem >> 3, cb = rem & 7;
            *(uint4*)&Ws[i >> 1][hh][cb * 8] =
                *(const uint4*)(wp + (size_t)(h0 + hh) * CC + ko + cb * 8);
        }
        for (int t = 0; t < TT; t++) {
            __syncthreads();
            #pragma unroll
            for (int i = 0; i < 2; i++) {
                int task = i * 256 + tx;
                int cb = task & 7, nr = task >> 3;
                unsigned long long d = *(const unsigned long long*)(
                    s1T + ((size_t)(b * TT + t) * NNv + n0 + nr) * CC + ko + cb * 8);
                *(uint4*)&Ss[nr][cb * 8] = spikes8_to_bf16(d);
            }
            __syncthreads();
            #pragma unroll
            for (int kb = 0; kb < 2; kb++) {
                bf16x8 s0f = *(const bf16x8*)&Ss[wn + ln][kb * 32 + q * 8];
                bf16x8 s1f = *(const bf16x8*)&Ss[wn + 16 + ln][kb * 32 + q * 8];
                #pragma unroll
                for (int s = 0; s < 3; s++) {
                    bf16x8 a0 = *(const bf16x8*)&Ws[s][wh + ln][kb * 32 + q * 8];
                    bf16x8 a1 = *(const bf16x8*)&Ws[s][wh + 16 + ln][kb * 32 + q * 8];
                    acc[t][0][0] = __builtin_amdgcn_mfma_f32_16x16x32_bf16(a0, s0f, acc[t][0][0], 0, 0, 0);
                    acc[t][0][1] = __builtin_amdgcn_mfma_f32_16x16x32_bf16(a0, s1f, acc[t][0][1], 0, 0, 0);
                    acc[t][1][0] = __builtin_amdgcn_mfma_f32_16x16x32_bf16(a1, s0f, acc[t][1][0], 0, 0, 0);
                    acc[t][1][1] = __builtin_amdgcn_mfma_f32_16x16x32_bf16(a1, s1f, acc[t][1][1], 0, 0, 0);
                }
            }
        }
    }

    // epilogue: bias + bn1 + LIF scan over t; write packed 4-byte spikes to s2T[b][l][h]
    #pragma unroll
    for (int mi = 0; mi < 2; mi++) {
        float invr[4], addr_[4], biasr[4];
        #pragma unroll
        for (int r = 0; r < 4; r++) {
            int h = h0 + wh + mi * 16 + q * 4 + r;
            float rsq = __fdiv_rn(1.0f, __fsqrt_rn(__fadd_rn(va1[h], 1e-5f)));
            invr[r] = __fmul_rn(g1[h], rsq);
            addr_[r] = __fsub_rn(be1[h], __fmul_rn(mu1[h], invr[r]));
            biasr[r] = b1[h];
        }
        #pragma unroll
        for (int ni = 0; ni < 2; ni++) {
            int l_n = n0 + wn + ni * 16 + ln;
            float v4[4] = {0.f, 0.f, 0.f, 0.f};
            #pragma unroll
            for (int t = 0; t < TT; t++) {
                unsigned int pk = 0;
                #pragma unroll
                for (int r = 0; r < 4; r++) {
                    float h1 = __fadd_rn(acc[t][mi][ni][r], biasr[r]);
                    float y  = __fadd_rn(__fmul_rn(h1, invr[r]), addr_[r]);
                    float vv = __fadd_rn(v4[r], __fdiv_rn(__fsub_rn(y, v4[r]), 1.5f));
                    bool sp = vv >= 1.0f;
                    v4[r] = sp ? 0.0f : vv;
                    if (sp) pk |= (1u << (8 * r));
                }
                *(unsigned int*)(s2T + ((size_t)b * LLv + t * NNv + l_n) * HH
                                 + h0 + wh + mi * 16 + q * 4) = pk;
            }
        }
    }
}

// ------------- GEMM2 (fc2) 2-split bf16 MFMA + bias, fp32 output -------------
__global__ __launch_bounds__(256) void k_gemm2(
    const unsigned short* __restrict__ w2h, const unsigned short* __restrict__ w2l,
    const float* __restrict__ b2c,
    const unsigned char* __restrict__ s2T, float* __restrict__ outp)
{
    __shared__ unsigned short Ws[2][64][136];
    __shared__ unsigned short Ss[64][136];
    const int tx = threadIdx.x;
    const int l0 = blockIdx.x * 64;
    const int c0 = blockIdx.y * 64;
    const int b  = blockIdx.z;
    const int lane = tx & 63, w = tx >> 6;
    const int q = lane >> 4, ln = lane & 15;
    const int wh = (w & 1) * 32, wn = (w >> 1) * 32;

    f32x4 acc[2][2];
    #pragma unroll
    for (int mi = 0; mi < 2; mi++)
    #pragma unroll
    for (int ni = 0; ni < 2; ni++)
        acc[mi][ni] = (f32x4){0.f, 0.f, 0.f, 0.f};

    for (int ko = 0; ko < HH; ko += 128) {
        __syncthreads();
        #pragma unroll
        for (int i = 0; i < 8; i++) {
            const unsigned short* wp = (i < 4) ? w2h : w2l;
            int rem = (i & 3) * 256 + tx;
            int cr = rem >> 4, kb8 = rem & 15;
            *(uint4*)&Ws[i >> 2][cr][kb8 * 8] =
                *(const uint4*)(wp + (size_t)(c0 + cr) * HH + ko + kb8 * 8);
        }
        #pragma unroll
        for (int i = 0; i < 4; i++) {
            int task = i * 256 + tx;
            int hb = task & 15, lr = task >> 4;
            unsigned long long d = *(const unsigned long long*)(
                s2T + ((size_t)b * LLv + l0 + lr) * HH + ko + hb * 8);
            *(uint4*)&Ss[lr][hb * 8] = spikes8_to_bf16(d);
        }
        __syncthreads();
        #pragma unroll
        for (int kb = 0; kb < 4; kb++) {
            bf16x8 s0f = *(const bf16x8*)&Ss[wn + ln][kb * 32 + q * 8];
            bf16x8 s1f = *(const bf16x8*)&Ss[wn + 16 + ln][kb * 32 + q * 8];
            #pragma unroll
            for (int s = 0; s < 2; s++) {
                bf16x8 a0 = *(const bf16x8*)&Ws[s][wh + ln][kb * 32 + q * 8];
                bf16x8 a1 = *(const bf16x8*)&Ws[s][wh + 16 + ln][kb * 32 + q * 8];
                acc[0][0] = __builtin_amdgcn_mfma_f32_16x16x32_bf16(a0, s0f, acc[0][0], 0, 0, 0);
                acc[0][1] = __builtin_amdgcn_mfma_f32_16x16x32_bf16(a0, s1f, acc[0][1], 0, 0, 0);
                acc[1][0] = __builtin_amdgcn_mfma_f32_16x16x32_bf16(a1, s0f, acc[1][0], 0, 0, 0);
                acc[1][1] = __builtin_amdgcn_mfma_f32_16x16x32_bf16(a1, s1f, acc[1][1], 0, 0, 0);
            }
        }
    }
    #pragma unroll
    for (int mi = 0; mi < 2; mi++)
    #pragma unroll
    for (int r = 0; r < 4; r++) {
        int c = c0 + wh + mi * 16 + q * 4 + r;
        float bias = b2c[c];
        #pragma unroll
        for (int ni = 0; ni < 2; ni++) {
            float o = __fadd_rn(acc[mi][ni][r], bias);
            outp[((size_t)b * CC + c) * LLv + l0 + wn + ni * 16 + ln] = o;
        }
    }
}

extern "C" void kernel_launch(void* const* d_in, const int* in_sizes, int n_in,
                              void* d_out, int out_size, void* d_ws, size_t ws_size,
                              hipStream_t stream) {
    const float* x    = (const float*)d_in[0];
    const float* fc1w = (const float*)d_in[1];
    const float* fc1b = (const float*)d_in[2];
    const float* fc2w = (const float*)d_in[3];
    const float* fc2b = (const float*)d_in[4];
    const float* g1   = (const float*)d_in[5];
    const float* be1  = (const float*)d_in[6];
    const float* mu1  = (const float*)d_in[7];
    const float* va1  = (const float*)d_in[8];
    const float* g2   = (const float*)d_in[9];
    const float* be2  = (const float*)d_in[10];
    const float* mu2  = (const float*)d_in[11];
    const float* va2  = (const float*)d_in[12];

    const size_t WN = (size_t)HH * CC;              // 262144 weights each
    unsigned short* w1h = (unsigned short*)d_ws;
    unsigned short* w1m = w1h + WN;
    unsigned short* w1l = w1m + WN;
    unsigned short* w2h = w1l + WN;
    unsigned short* w2l = w2h + WN;
    unsigned char*  s1T = (unsigned char*)(w2l + WN);          // 33.5 MB
    unsigned char*  s2T = s1T + (size_t)BB * CC * LLv;         // 134 MB
    unsigned char*  s1  = s2T;   // alias: s1 dead after k_transpose, before gemm1 writes s2T
    float* outp = (float*)d_out;

    hipLaunchKernelGGL(k_split3, dim3(WN / 256), dim3(256), 0, stream, fc1w, w1h, w1m, w1l, (int)WN);
    hipLaunchKernelGGL(k_split2, dim3(WN / 256), dim3(256), 0, stream, fc2w, w2h, w2l, (int)WN);
    hipLaunchKernelGGL(k_bn2_lif, dim3((BB * CC * NNv / 8) / 256), dim3(256), 0, stream,
                       x, g2, be2, mu2, va2, s1);
    hipLaunchKernelGGL(k_transpose, dim3(NNv / 64, CC / 64, BB * TT), dim3(256), 0, stream, s1, s1T);
    hipLaunchKernelGGL(k_gemm1_lif, dim3(NNv / 64, HH / 64, BB), dim3(256), 0, stream,
                       w1h, w1m, w1l, fc1b, g1, be1, mu1, va1, s1T, s2T);
    hipLaunchKernelGGL(k_gemm2, dim3(LLv / 64, CC / 64, BB), dim3(256), 0, stream,
                       w2h, w2l, fc2b, s2T, outp);
}

// Round 4
// 622.214 us; speedup vs baseline: 1.7022x; 1.1404x over previous
//
#include <hip/hip_runtime.h>

#define BB 8
#define CC 256
#define TT 4
#define NNv 4096
#define HH 1024
#define LLv (TT*NNv)   // 16384

typedef short bf16x8 __attribute__((ext_vector_type(8)));
typedef float f32x4 __attribute__((ext_vector_type(4)));

static __device__ __forceinline__ float bfbits2f(unsigned short h) {
    return __uint_as_float(((unsigned int)h) << 16);
}
static __device__ __forceinline__ unsigned short f2bf(float f) {
    unsigned int u = __float_as_uint(f);
    return (unsigned short)((u + 0x7FFFu + ((u >> 16) & 1u)) >> 16);
}
// byte j of a group-of-8 lands at fragment slot p = permpos(j); the spike
// expansion below emits source bytes in order {0,2,4,6,1,3,5,7} at slots 0..7.
static __device__ __forceinline__ int permpos(int j) { return (j >> 1) + ((j & 1) << 2); }

// byte->bf16 {0,1}: slot p holds source byte perm[p], perm = {0,2,4,6,1,3,5,7}
static __device__ __forceinline__ uint4 spikes8_to_bf16(unsigned long long d) {
    unsigned int lo = (unsigned int)d, hi = (unsigned int)(d >> 32);
    uint4 o;
    o.x = (lo & 0x10001u) * 0x3F80u;
    o.y = (hi & 0x10001u) * 0x3F80u;
    o.z = ((lo >> 8) & 0x10001u) * 0x3F80u;
    o.w = ((hi >> 8) & 0x10001u) * 0x3F80u;
    return o;
}

// ---- fc1 weights -> fragment-linear 3-split (hi/mid/lo), k-permuted ----
// dst: ((((ht*4+ko)*2+kb)*4+g)*64 + q*16+ln)*8 + p   (+ s*262144)
__global__ __launch_bounds__(256) void k_prep1(const float* __restrict__ w,
                                               unsigned short* __restrict__ wf)
{
    int i = blockIdx.x * 256 + threadIdx.x;        // i = h*256 + c
    int h = i >> 8, c = i & 255;
    int ht = h >> 6, hr = h & 63, g = hr >> 4, ln = hr & 15;
    int ko = c >> 6, cr = c & 63, kb = cr >> 5, q = (cr >> 3) & 3, j = c & 7;
    size_t base = (((((size_t)ht * 4 + ko) * 2 + kb) * 4 + g) * 64 + q * 16 + ln) * 8 + permpos(j);
    const size_t WS = 262144;
    float x = w[i];
    unsigned short hi = f2bf(x); float r  = __fsub_rn(x, bfbits2f(hi));
    unsigned short md = f2bf(r); float r2 = __fsub_rn(r, bfbits2f(md));
    unsigned short lo = f2bf(r2);
    wf[base] = hi; wf[WS + base] = md; wf[2 * WS + base] = lo;
}

// ---- fc2 weights -> fragment-linear 2-split (hi/lo), k-permuted ----
// dst: ((((ct*8+ko)*4+kb)*4+g)*64 + q*16+ln)*8 + p   (+ s*262144)
__global__ __launch_bounds__(256) void k_prep2(const float* __restrict__ w,
                                               unsigned short* __restrict__ wf)
{
    int i = blockIdx.x * 256 + threadIdx.x;        // i = c*1024 + h
    int c = i >> 10, h = i & 1023;
    int ct = c >> 6, cr = c & 63, g = cr >> 4, ln = cr & 15;
    int ko = h >> 7, hr = h & 127, kb = hr >> 5, q = (hr >> 3) & 3, j = h & 7;
    size_t base = (((((size_t)ct * 8 + ko) * 4 + kb) * 4 + g) * 64 + q * 16 + ln) * 8 + permpos(j);
    const size_t WS = 262144;
    float x = w[i];
    unsigned short hi = f2bf(x); float r = __fsub_rn(x, bfbits2f(hi));
    unsigned short lo = f2bf(r);
    wf[base] = hi; wf[WS + base] = lo;
}

// ---- bn2 + LIF over T + transpose: x[b][c][t][n] -> s1T[b][t][n][c] bytes ----
__global__ __launch_bounds__(256) void k_bn2_lif_t(
    const float* __restrict__ x,
    const float* __restrict__ g, const float* __restrict__ be,
    const float* __restrict__ mu, const float* __restrict__ va,
    unsigned char* __restrict__ s1T)
{
    __shared__ unsigned char ts[TT][64][80];       // [t][c][n], stride 80 (16B-aligned)
    int tx = threadIdx.x;
    int n0 = blockIdx.x * 64;
    int c0 = blockIdx.y * 64;
    int b  = blockIdx.z;
    int cl = tx >> 2, np = tx & 3;
    int c = c0 + cl;
    float rsq = __fdiv_rn(1.0f, __fsqrt_rn(__fadd_rn(va[c], 1e-5f)));
    float inv = __fmul_rn(g[c], rsq);
    float add = __fsub_rn(be[c], __fmul_rn(mu[c], inv));
    size_t xb = ((size_t)(b * CC + c) * TT) * NNv + n0 + np * 16;
    float v[16];
    #pragma unroll
    for (int i = 0; i < 16; i++) v[i] = 0.0f;
    #pragma unroll
    for (int t = 0; t < TT; t++) {
        float4 p[4];
        #pragma unroll
        for (int k = 0; k < 4; k++) p[k] = *(const float4*)(x + xb + (size_t)t * NNv + 4 * k);
        const float* xp = (const float*)p;
        unsigned int ob[4] = {0, 0, 0, 0};
        #pragma unroll
        for (int i = 0; i < 16; i++) {
            float y = __fadd_rn(__fmul_rn(xp[i], inv), add);
            float vv = __fadd_rn(v[i], __fdiv_rn(__fsub_rn(y, v[i]), 1.5f));
            bool sp = vv >= 1.0f;
            v[i] = sp ? 0.0f : vv;
            if (sp) ob[i >> 2] |= 1u << (8 * (i & 3));
        }
        uint4 pk; pk.x = ob[0]; pk.y = ob[1]; pk.z = ob[2]; pk.w = ob[3];
        *(uint4*)&ts[t][cl][np * 16] = pk;
    }
    __syncthreads();
    int nl = tx >> 2, cp = tx & 3;
    #pragma unroll
    for (int t = 0; t < TT; t++) {
        unsigned int u[4];
        #pragma unroll
        for (int kk = 0; kk < 4; kk++) {
            u[kk] = (unsigned int)ts[t][cp * 16 + kk * 4 + 0][nl]
                  | ((unsigned int)ts[t][cp * 16 + kk * 4 + 1][nl] << 8)
                  | ((unsigned int)ts[t][cp * 16 + kk * 4 + 2][nl] << 16)
                  | ((unsigned int)ts[t][cp * 16 + kk * 4 + 3][nl] << 24);
        }
        uint4 pk; pk.x = u[0]; pk.y = u[1]; pk.z = u[2]; pk.w = u[3];
        *(uint4*)(s1T + ((size_t)(b * TT + t) * NNv + n0 + nl) * CC + c0 + cp * 16) = pk;
    }
}

// ------- GEMM1 (fc1) 3-split, W-frags from global, spikes-only LDS, fused bn1+LIF -------
__global__ __launch_bounds__(256) void k_gemm1_lif(
    const unsigned short* __restrict__ w1f,
    const float* __restrict__ b1,
    const float* __restrict__ g1, const float* __restrict__ be1,
    const float* __restrict__ mu1, const float* __restrict__ va1,
    const unsigned char* __restrict__ s1T, unsigned char* __restrict__ s2T)
{
    __shared__ unsigned short Ss[TT][64][72];
    const int tx = threadIdx.x;
    const int n0 = blockIdx.x * 64;
    const int ht = blockIdx.y;
    const int b  = blockIdx.z;
    const int lane = tx & 63, w = tx >> 6;
    const int q = lane >> 4, ln = lane & 15;
    const int mh = (w & 1) * 32, wn = (w >> 1) * 32;
    const int h0 = ht * 64;
    const size_t WS = 262144;

    f32x4 acc[TT][2][2];
    #pragma unroll
    for (int t = 0; t < TT; t++)
    #pragma unroll
    for (int mi = 0; mi < 2; mi++)
    #pragma unroll
    for (int ni = 0; ni < 2; ni++)
        acc[t][mi][ni] = (f32x4){0.f, 0.f, 0.f, 0.f};

    for (int ko = 0; ko < 4; ko++) {
        __syncthreads();
        #pragma unroll
        for (int i = 0; i < 8; i++) {
            int task = i * 256 + tx;
            int cb = task & 7, nr = (task >> 3) & 63, t = task >> 9;
            unsigned long long d = *(const unsigned long long*)(
                s1T + ((size_t)(b * TT + t) * NNv + n0 + nr) * CC + ko * 64 + cb * 8);
            *(uint4*)&Ss[t][nr][cb * 8] = spikes8_to_bf16(d);
        }
        __syncthreads();
        #pragma unroll
        for (int kb = 0; kb < 2; kb++) {
            bf16x8 wf[2][3];
            #pragma unroll
            for (int mi = 0; mi < 2; mi++) {
                int gg = (mh >> 4) + mi;
                size_t fbase = (((((size_t)ht * 4 + ko) * 2 + kb) * 4 + gg) * 64 + lane) * 8;
                #pragma unroll
                for (int s = 0; s < 3; s++)
                    wf[mi][s] = *(const bf16x8*)(w1f + s * WS + fbase);
            }
            #pragma unroll
            for (int t = 0; t < TT; t++) {
                bf16x8 sf0 = *(const bf16x8*)&Ss[t][wn + ln][kb * 32 + q * 8];
                bf16x8 sf1 = *(const bf16x8*)&Ss[t][wn + 16 + ln][kb * 32 + q * 8];
                #pragma unroll
                for (int s = 0; s < 3; s++) {
                    acc[t][0][0] = __builtin_amdgcn_mfma_f32_16x16x32_bf16(wf[0][s], sf0, acc[t][0][0], 0, 0, 0);
                    acc[t][0][1] = __builtin_amdgcn_mfma_f32_16x16x32_bf16(wf[0][s], sf1, acc[t][0][1], 0, 0, 0);
                    acc[t][1][0] = __builtin_amdgcn_mfma_f32_16x16x32_bf16(wf[1][s], sf0, acc[t][1][0], 0, 0, 0);
                    acc[t][1][1] = __builtin_amdgcn_mfma_f32_16x16x32_bf16(wf[1][s], sf1, acc[t][1][1], 0, 0, 0);
                }
            }
        }
    }

    // epilogue: bias + bn1 + LIF scan over t; packed 4-byte spike stores to s2T[b][l][h]
    #pragma unroll
    for (int mi = 0; mi < 2; mi++) {
        float invr[4], addr_[4], biasr[4];
        #pragma unroll
        for (int r = 0; r < 4; r++) {
            int h = h0 + mh + mi * 16 + q * 4 + r;
            float rsq = __fdiv_rn(1.0f, __fsqrt_rn(__fadd_rn(va1[h], 1e-5f)));
            invr[r] = __fmul_rn(g1[h], rsq);
            addr_[r] = __fsub_rn(be1[h], __fmul_rn(mu1[h], invr[r]));
            biasr[r] = b1[h];
        }
        #pragma unroll
        for (int ni = 0; ni < 2; ni++) {
            int l_n = n0 + wn + ni * 16 + ln;
            float v4[4] = {0.f, 0.f, 0.f, 0.f};
            #pragma unroll
            for (int t = 0; t < TT; t++) {
                unsigned int pk = 0;
                #pragma unroll
                for (int r = 0; r < 4; r++) {
                    float h1 = __fadd_rn(acc[t][mi][ni][r], biasr[r]);
                    float y  = __fadd_rn(__fmul_rn(h1, invr[r]), addr_[r]);
                    float vv = __fadd_rn(v4[r], __fdiv_rn(__fsub_rn(y, v4[r]), 1.5f));
                    bool sp = vv >= 1.0f;
                    v4[r] = sp ? 0.0f : vv;
                    if (sp) pk |= (1u << (8 * r));
                }
                *(unsigned int*)(s2T + ((size_t)b * LLv + t * NNv + l_n) * HH
                                 + h0 + mh + mi * 16 + q * 4) = pk;
            }
        }
    }
}

// ------- GEMM2 (fc2) 2-split, W-frags from global, spikes-only LDS, fp32 out -------
__global__ __launch_bounds__(256) void k_gemm2(
    const unsigned short* __restrict__ w2f,
    const float* __restrict__ b2c,
    const unsigned char* __restrict__ s2T, float* __restrict__ outp)
{
    __shared__ unsigned short Ss[128][136];
    const int tx = threadIdx.x;
    const int l0 = blockIdx.x * 128;
    const int ct = blockIdx.y;
    const int b  = blockIdx.z;
    const int lane = tx & 63, w = tx >> 6;
    const int q = lane >> 4, ln = lane & 15;
    const int mc = (w & 1) * 32, wl = (w >> 1) * 64;
    const size_t WS = 262144;

    f32x4 acc[2][4];
    #pragma unroll
    for (int mi = 0; mi < 2; mi++)
    #pragma unroll
    for (int ni = 0; ni < 4; ni++)
        acc[mi][ni] = (f32x4){0.f, 0.f, 0.f, 0.f};

    for (int ko = 0; ko < 8; ko++) {
        __syncthreads();
        #pragma unroll
        for (int i = 0; i < 8; i++) {
            int task = i * 256 + tx;
            int hb = task & 15, lr = task >> 4;
            unsigned long long d = *(const unsigned long long*)(
                s2T + ((size_t)b * LLv + l0 + lr) * HH + ko * 128 + hb * 8);
            *(uint4*)&Ss[lr][hb * 8] = spikes8_to_bf16(d);
        }
        __syncthreads();
        #pragma unroll
        for (int kb = 0; kb < 4; kb++) {
            bf16x8 wf[2][2];
            #pragma unroll
            for (int mi = 0; mi < 2; mi++) {
                int gg = (mc >> 4) + mi;
                size_t fbase = (((((size_t)ct * 8 + ko) * 4 + kb) * 4 + gg) * 64 + lane) * 8;
                #pragma unroll
                for (int s = 0; s < 2; s++)
                    wf[mi][s] = *(const bf16x8*)(w2f + s * WS + fbase);
            }
            bf16x8 sf[4];
            #pragma unroll
            for (int ni = 0; ni < 4; ni++)
                sf[ni] = *(const bf16x8*)&Ss[wl + ni * 16 + ln][kb * 32 + q * 8];
            #pragma unroll
            for (int s = 0; s < 2; s++)
            #pragma unroll
            for (int mi = 0; mi < 2; mi++)
            #pragma unroll
            for (int ni = 0; ni < 4; ni++)
                acc[mi][ni] = __builtin_amdgcn_mfma_f32_16x16x32_bf16(wf[mi][s], sf[ni], acc[mi][ni], 0, 0, 0);
        }
    }
    #pragma unroll
    for (int mi = 0; mi < 2; mi++)
    #pragma unroll
    for (int r = 0; r < 4; r++) {
        int c = ct * 64 + mc + mi * 16 + q * 4 + r;
        float bias = b2c[c];
        #pragma unroll
        for (int ni = 0; ni < 4; ni++) {
            int l = l0 + wl + ni * 16 + ln;
            outp[((size_t)b * CC + c) * LLv + l] = __fadd_rn(acc[mi][ni][r], bias);
        }
    }
}

extern "C" void kernel_launch(void* const* d_in, const int* in_sizes, int n_in,
                              void* d_out, int out_size, void* d_ws, size_t ws_size,
                              hipStream_t stream) {
    const float* x    = (const float*)d_in[0];
    const float* fc1w = (const float*)d_in[1];
    const float* fc1b = (const float*)d_in[2];
    const float* fc2w = (const float*)d_in[3];
    const float* fc2b = (const float*)d_in[4];
    const float* g1   = (const float*)d_in[5];
    const float* be1  = (const float*)d_in[6];
    const float* mu1  = (const float*)d_in[7];
    const float* va1  = (const float*)d_in[8];
    const float* g2   = (const float*)d_in[9];
    const float* be2  = (const float*)d_in[10];
    const float* mu2  = (const float*)d_in[11];
    const float* va2  = (const float*)d_in[12];

    unsigned short* w1f = (unsigned short*)d_ws;               // 3*262144 shorts
    unsigned short* w2f = w1f + (size_t)3 * 262144;            // 2*262144 shorts
    unsigned char*  s1T = (unsigned char*)(w2f + (size_t)2 * 262144);  // 33.5 MB
    unsigned char*  s2T = s1T + (size_t)BB * CC * LLv;                 // 134 MB
    float* outp = (float*)d_out;

    hipLaunchKernelGGL(k_prep1, dim3(1024), dim3(256), 0, stream, fc1w, w1f);
    hipLaunchKernelGGL(k_prep2, dim3(1024), dim3(256), 0, stream, fc2w, w2f);
    hipLaunchKernelGGL(k_bn2_lif_t, dim3(NNv / 64, CC / 64, BB), dim3(256), 0, stream,
                       x, g2, be2, mu2, va2, s1T);
    hipLaunchKernelGGL(k_gemm1_lif, dim3(NNv / 64, HH / 64, BB), dim3(256), 0, stream,
                       w1f, fc1b, g1, be1, mu1, va1, s1T, s2T);
    hipLaunchKernelGGL(k_gemm2, dim3(LLv / 128, CC / 64, BB), dim3(256), 0, stream,
                       w2f, fc2b, s2T, outp);
}